// Round 1
// baseline (145.384 us; speedup 1.0000x reference)
//
#include <hip/hip_runtime.h>
#include <hip/hip_bf16.h>

// Problem constants (from reference)
#define N_OUT 4096
#define N_IN  4096
#define N_SP  1024
#define MROWS 8192   // BATCH*SEQ = 4*2048

// GEMM tile (m97 structure: 128x128 tile, BK=32, 4 waves 2x2)
#define BM 128
#define BN 128
#define BK 32

typedef __attribute__((ext_vector_type(8))) short bf16x8;  // 8 bf16 = 4 VGPRs
typedef __attribute__((ext_vector_type(4))) float f32x4;   // MFMA 16x16 accumulator

__device__ __forceinline__ unsigned short f2bf(float f) {
  // round-to-nearest-even bf16 (inputs are finite normals; no NaN handling needed)
  union { float f; unsigned int u; } c; c.f = f;
  unsigned int lsb = (c.u >> 16) & 1u;
  c.u += 0x7fffu + lsb;
  return (unsigned short)(c.u >> 16);
}

__device__ __forceinline__ void gload_lds16(const void* g, void* l) {
  __builtin_amdgcn_global_load_lds(
      (const __attribute__((address_space(1))) void*)g,
      (__attribute__((address_space(3))) void*)l, 16, 0, 0);
}

// ---------------------------------------------------------------------------
// Pass 1a: gather x columns per sparse_idx and convert to bf16.
//   x  : [MROWS, N_IN] f32
//   xg : [MROWS, N_SP] bf16
// idx dtype is detected at runtime (int32 per harness convention, int64 per
// reference decl). Reading idx_raw[0] as int64 is in-bounds for either dtype;
// for a real int32 array the value is idx0|(idx1<<32) >= 2^32 (sorted unique,
// idx1 >= 1), so `< N_IN` discriminates safely.
// ---------------------------------------------------------------------------
__global__ __launch_bounds__(256) void gather_x(const float* __restrict__ x,
                                                const void* __restrict__ idx_raw,
                                                unsigned short* __restrict__ xg) {
  const long long* p64 = (const long long*)idx_raw;
  const int* p32 = (const int*)idx_raw;
  const bool is64 = ((unsigned long long)p64[0]) < (unsigned long long)N_IN;

  const int m = blockIdx.x;
  const float* row = x + (size_t)m * N_IN;
  unsigned short* orow = xg + (size_t)m * N_SP;

  int k = threadIdx.x;
  if (is64) {
#pragma unroll
    for (int i = 0; i < 4; ++i, k += 256) {
      orow[k] = f2bf(row[(int)p64[k]]);
    }
  } else {
#pragma unroll
    for (int i = 0; i < 4; ++i, k += 256) {
      orow[k] = f2bf(row[p32[k]]);
    }
  }
}

// ---------------------------------------------------------------------------
// Pass 1b: convert sparse_values [N_OUT, N_SP] f32 -> bf16 (K-contiguous "B^T")
// ---------------------------------------------------------------------------
__global__ __launch_bounds__(256) void cvt_w(const float* __restrict__ w,
                                             unsigned short* __restrict__ wb) {
  const int i = blockIdx.x * 256 + threadIdx.x;   // each thread: 4 elems
  float4 v = ((const float4*)w)[i];
  ushort4 o;
  o.x = f2bf(v.x); o.y = f2bf(v.y); o.z = f2bf(v.z); o.w = f2bf(v.w);
  ((ushort4*)wb)[i] = o;
}

// ---------------------------------------------------------------------------
// Pass 2: bf16 GEMM, C[m,n] = sum_k A[m,k]*B[n,k]
//   A: [MROWS, N_SP] bf16 row-major (K-contiguous)
//   B: [N_OUT, N_SP] bf16 row-major (K-contiguous)  -- "NT" layout
//   C: [MROWS, N_OUT] f32
// m97 structure: global_load_lds width-16 staging, single-buffered LDS,
// 16x16x32 bf16 MFMA, 4 waves each owning a 64x64 output quadrant.
// ---------------------------------------------------------------------------
__global__ __launch_bounds__(256) void gemm_bt(const unsigned short* __restrict__ A,
                                               const unsigned short* __restrict__ B,
                                               float* __restrict__ C) {
  __shared__ unsigned short As[BM * BK];  // 8 KiB, row-major [128][32]
  __shared__ unsigned short Bs[BN * BK];  // 8 KiB, row-major [128][32]

  const int K = N_SP;
  const int bn = blockIdx.x;   // 0..31  (N tiles)
  const int bm = blockIdx.y;   // 0..63  (M tiles)
  const int tid = threadIdx.x;
  const int wave = tid >> 6, lane = tid & 63;
  const int wr = wave >> 1, wc = wave & 1;    // 2x2 wave grid
  const int l15 = lane & 15, lq = lane >> 4;  // fragment lane decomposition

  // Staging: thread t moves 16B (8 bf16 along K). row = t/4, kchunk = t%4.
  // LDS dest byte offset = t*16 (linear in lane order -> valid for
  // global_load_lds wave-uniform-base + lane*16 semantics).
  const int r  = tid >> 2;          // 0..63 (half-tile row)
  const int kc = (tid & 3) << 3;    // bf16 offset within row: 0,8,16,24

  const unsigned short* Ab = A + (size_t)(bm * BM + r) * K + kc;
  const unsigned short* Bb = B + (size_t)(bn * BN + r) * K + kc;
  unsigned short* AsDst0 = As + tid * 8;         // rows 0..63
  unsigned short* AsDst1 = As + 2048 + tid * 8;  // rows 64..127
  unsigned short* BsDst0 = Bs + tid * 8;
  unsigned short* BsDst1 = Bs + 2048 + tid * 8;

  f32x4 acc[4][4] = {};  // 4x4 fragments of 16x16 per wave = 64x64

  for (int kt = 0; kt < K; kt += BK) {
    gload_lds16(Ab + kt, AsDst0);
    gload_lds16(Ab + (size_t)64 * K + kt, AsDst1);
    gload_lds16(Bb + kt, BsDst0);
    gload_lds16(Bb + (size_t)64 * K + kt, BsDst1);
    __syncthreads();  // compiler emits vmcnt(0) drain before s_barrier

    bf16x8 af[4], bfr[4];
#pragma unroll
    for (int m = 0; m < 4; ++m)
      af[m] = *(const bf16x8*)&As[(wr * 64 + m * 16 + l15) * BK + lq * 8];
#pragma unroll
    for (int n = 0; n < 4; ++n)
      bfr[n] = *(const bf16x8*)&Bs[(wc * 64 + n * 16 + l15) * BK + lq * 8];

#pragma unroll
    for (int m = 0; m < 4; ++m)
#pragma unroll
      for (int n = 0; n < 4; ++n)
        acc[m][n] = __builtin_amdgcn_mfma_f32_16x16x32_bf16(af[m], bfr[n], acc[m][n], 0, 0, 0);

    __syncthreads();
  }

  // Epilogue. C/D layout (m89-verified): col = lane&15, row = (lane>>4)*4 + reg.
  float* Cb = C + (size_t)(bm * BM + wr * 64 + lq * 4) * N_OUT
                + (size_t)(bn * BN + wc * 64 + l15);
#pragma unroll
  for (int m = 0; m < 4; ++m)
#pragma unroll
    for (int n = 0; n < 4; ++n)
#pragma unroll
      for (int j = 0; j < 4; ++j)
        Cb[(size_t)(m * 16 + j) * N_OUT + n * 16] = acc[m][n][j];
}

extern "C" void kernel_launch(void* const* d_in, const int* in_sizes, int n_in,
                              void* d_out, int out_size, void* d_ws, size_t ws_size,
                              hipStream_t stream) {
  const float* x   = (const float*)d_in[0];   // [4,2048,4096] f32
  const float* sv  = (const float*)d_in[1];   // [4096,1024] f32
  const void*  idx = d_in[2];                 // [1024] int32 or int64
  float* out = (float*)d_out;                 // [4,2048,4096] f32

  // workspace: xg bf16 [8192,1024] = 16 MiB, wb bf16 [4096,1024] = 8 MiB
  unsigned short* xg = (unsigned short*)d_ws;
  unsigned short* wb = xg + (size_t)MROWS * N_SP;

  gather_x<<<MROWS, 256, 0, stream>>>(x, idx, xg);
  cvt_w<<<(N_OUT * N_SP / 4) / 256, 256, 0, stream>>>(sv, wb);

  dim3 grid(N_OUT / BN, MROWS / BM);  // (32, 64) = 2048 blocks
  gemm_bt<<<grid, 256, 0, stream>>>(xg, wb, out);
}

// Round 2
// 111.832 us; speedup vs baseline: 1.3000x; 1.3000x over previous
//
#include <hip/hip_runtime.h>
#include <hip/hip_bf16.h>

// Problem constants
#define NOUT  4096
#define KDIM  1024   // N_SPARSE
#define MROWS 8192   // BATCH*SEQ

typedef __attribute__((ext_vector_type(8))) short bf16x8;  // 8 bf16 = 4 VGPRs
typedef __attribute__((ext_vector_type(4))) float f32x4;   // MFMA 16x16 accumulator

__device__ __forceinline__ unsigned short f2bf(float f) {
  union { float f; unsigned int u; } c; c.f = f;
  unsigned int lsb = (c.u >> 16) & 1u;
  c.u += 0x7fffu + lsb;
  return (unsigned short)(c.u >> 16);
}

__device__ __forceinline__ void gload_lds16(const void* g, void* l) {
  __builtin_amdgcn_global_load_lds(
      (const __attribute__((address_space(1))) void*)g,
      (__attribute__((address_space(3))) void*)l, 16, 0, 0);
}

#define FENCE() asm volatile("" ::: "memory")
#define BAR() do { FENCE(); __builtin_amdgcn_s_barrier(); FENCE(); } while (0)
#define VMW(n) asm volatile("s_waitcnt vmcnt(" #n ")" ::: "memory")

// ---------------------------------------------------------------------------
// Pass 1a: gather x columns per sparse_idx -> bf16. Coalesced float4 row load
// into LDS, then LDS-gather (removes scattered global loads).
// ---------------------------------------------------------------------------
__global__ __launch_bounds__(256) void gather_x(const float* __restrict__ x,
                                                const void* __restrict__ idx_raw,
                                                unsigned short* __restrict__ xg) {
  __shared__ float row[NOUT == 0 ? 1 : 4096];
  __shared__ int sidx[1024];
  const long long* p64 = (const long long*)idx_raw;
  const int* p32 = (const int*)idx_raw;
  // int64 vs int32 detection: for int32 data, element0-as-int64 >= 2^32
  // (sorted unique indices, second word >= 1), so `< 4096` discriminates.
  const bool is64 = ((unsigned long long)p64[0]) < 4096ull;
  const int t = threadIdx.x;
  const int m = blockIdx.x;
  const float* src = x + (size_t)m * 4096;
#pragma unroll
  for (int i = 0; i < 4; ++i)
    ((float4*)row)[t + 256 * i] = ((const float4*)src)[t + 256 * i];
  if (is64) {
#pragma unroll
    for (int i = 0; i < 4; ++i) sidx[t + 256 * i] = (int)p64[t + 256 * i];
  } else {
#pragma unroll
    for (int i = 0; i < 4; ++i) sidx[t + 256 * i] = p32[t + 256 * i];
  }
  __syncthreads();
  unsigned short* dst = xg + (size_t)m * 1024;
#pragma unroll
  for (int i = 0; i < 4; ++i) {
    int k = t + 256 * i;
    dst[k] = f2bf(row[sidx[k]]);
  }
}

// ---------------------------------------------------------------------------
// Pass 1b: sparse_values [4096,1024] f32 -> bf16
// ---------------------------------------------------------------------------
__global__ __launch_bounds__(256) void cvt_w(const float* __restrict__ w,
                                             unsigned short* __restrict__ wb) {
  const int i = blockIdx.x * 256 + threadIdx.x;
  float4 v = ((const float4*)w)[i];
  ushort4 o;
  o.x = f2bf(v.x); o.y = f2bf(v.y); o.z = f2bf(v.z); o.w = f2bf(v.w);
  ((ushort4*)wb)[i] = o;
}

// ---------------------------------------------------------------------------
// Pass 2: 256x256 8-phase bf16 GEMM (T2+T3+T4+T5), C[m,n] = sum_k A[m,k]B[n,k]
//   A: [8192,1024] bf16 row-major, B: [4096,1024] bf16 row-major, C: f32.
// 512 threads = 8 waves (2M x 4N), per-wave output 128x64, BK=64, K-tiles=16,
// 2 K-tiles per iteration (buf0 even, buf1 odd), LDS 128 KiB.
// Swizzle: 16B-chunk index XOR (row&7), applied on global source (staging)
// and ds_read address; LDS destination stays linear (rule #21).
// ---------------------------------------------------------------------------
__global__ __launch_bounds__(512, 2) void gemm256(const unsigned short* __restrict__ A,
                                                  const unsigned short* __restrict__ B,
                                                  float* __restrict__ C) {
  __shared__ __align__(16) unsigned short lds[65536];  // 128 KiB

  const int tid = threadIdx.x;
  const int lane = tid & 63;
  const int wid = tid >> 6;
  const int wm = wid >> 2, wn = wid & 3;       // 2 x 4 wave grid
  const int l15 = lane & 15, lq = lane >> 4;
  const int swz = l15 & 7;

  const int bn0 = blockIdx.x * 256;
  const int bm0 = blockIdx.y * 256;

  // ---- staging constants: thread covers LDS 16B-chunk tid within each
  // 64-row round; row-in-round r0, lds-chunk cl=tid&7, global chunk cg=cl^(r0&7)
  const int r0 = tid >> 3;
  const int cg = (tid & 7) ^ (r0 & 7);
  const unsigned short* Ag = A + (size_t)(bm0 + r0) * KDIM + cg * 8;
  const unsigned short* Bg = B + (size_t)(bn0 + r0) * KDIM + cg * 8;
  const int tid8 = tid * 8;

  // ---- ds_read constants (ushort offsets). Row term (rows within half-tile):
  // (mh*64 + mf*16 + l15)*64 ; chunk term: ((ks*4+lq)^swz)*8
  const int cA0 = (lq ^ swz) * 8;   // ks=0
  const int cA1 = cA0 ^ 32;         // ks=1  ((c^4)*8 == c*8 ^ 32)
  const int aOff = wm * 8192 + l15 * 64;                       // + D*16384 + mh*4096
  const int bOff = 32768 + (wn >> 1) * 8192 + (wn & 1) * 4096 + l15 * 64;  // + D*16384 + nh*2048

  f32x4 acc[8][4] = {};
  bf16x8 a0[4], a1[4], bA0[2], bA1[2], bB0[2], bB1[2];

#define LOAD_A(D, MH) do {                                                       \
    const unsigned short* _p = lds + (D) * 16384 + aOff + (MH) * 4096;           \
    a0[0] = *(const bf16x8*)(_p + cA0);        a1[0] = *(const bf16x8*)(_p + cA1);        \
    a0[1] = *(const bf16x8*)(_p + 1024 + cA0); a1[1] = *(const bf16x8*)(_p + 1024 + cA1); \
    a0[2] = *(const bf16x8*)(_p + 2048 + cA0); a1[2] = *(const bf16x8*)(_p + 2048 + cA1); \
    a0[3] = *(const bf16x8*)(_p + 3072 + cA0); a1[3] = *(const bf16x8*)(_p + 3072 + cA1); \
  } while (0)

#define LOAD_B(D, NH, B0, B1) do {                                               \
    const unsigned short* _p = lds + (D) * 16384 + bOff + (NH) * 2048;           \
    B0[0] = *(const bf16x8*)(_p + cA0);        B1[0] = *(const bf16x8*)(_p + cA1);        \
    B0[1] = *(const bf16x8*)(_p + 1024 + cA0); B1[1] = *(const bf16x8*)(_p + 1024 + cA1); \
  } while (0)

#define STAGE_A(D, T, H) do {                                                                  \
    gload_lds16(Ag + (size_t)((H) * 128) * KDIM + (T) * 64,                                    \
                lds + (D) * 16384 + (H) * 8192 + tid8);                                        \
    gload_lds16(Ag + (size_t)((H) * 128 + 64) * KDIM + (T) * 64,                               \
                lds + (D) * 16384 + (H) * 8192 + 4096 + tid8);                                 \
  } while (0)

#define STAGE_B(D, T, H) do {                                                                  \
    gload_lds16(Bg + (size_t)((H) * 128) * KDIM + (T) * 64,                                    \
                lds + 32768 + (D) * 16384 + (H) * 8192 + tid8);                                \
    gload_lds16(Bg + (size_t)((H) * 128 + 64) * KDIM + (T) * 64,                               \
                lds + 32768 + (D) * 16384 + (H) * 8192 + 4096 + tid8);                         \
  } while (0)

#define MFMA_Q(MH, NH, B0, B1) do {                                                            \
    __builtin_amdgcn_s_setprio(1);                                                             \
    _Pragma("unroll") for (int mf = 0; mf < 4; ++mf) {                                         \
      _Pragma("unroll") for (int nf = 0; nf < 2; ++nf) {                                       \
        acc[(MH)*4+mf][(NH)*2+nf] = __builtin_amdgcn_mfma_f32_16x16x32_bf16(                   \
            a0[mf], B0[nf], acc[(MH)*4+mf][(NH)*2+nf], 0, 0, 0);                               \
        acc[(MH)*4+mf][(NH)*2+nf] = __builtin_amdgcn_mfma_f32_16x16x32_bf16(                   \
            a1[mf], B1[nf], acc[(MH)*4+mf][(NH)*2+nf], 0, 0, 0);                               \
      }                                                                                        \
    }                                                                                          \
    __builtin_amdgcn_s_setprio(0);                                                             \
  } while (0)

  // ---- prologue: tile0 (buf0) fully + tile1 (buf1) B-halves; keep tile1's
  // B loads (4) in flight across the gate.
  STAGE_B(0, 0, 0); STAGE_B(0, 0, 1);
  STAGE_A(0, 0, 0); STAGE_A(0, 0, 1);
  STAGE_B(1, 1, 0); STAGE_B(1, 1, 1);
  VMW(4);
  BAR();

  // ---- main loop: iteration i computes K-tiles 2i (buf0, P1-P4) and 2i+1
  // (buf1, P5-P8). Stage slots chosen so every overwritten half-tile is dead:
  // buf0 B dies after P2 -> staged P3,P4 ; buf0 A dies after P3 -> P5,P6 ;
  // buf1 B dies after P6 -> P7,P8 ; buf1 A dies after P7 -> next-iter P1,P2.
  // vmcnt(4) at P4 (gates buf1's 8 loads, leaves P3/P4's 4 in flight) and at
  // P8 (gates buf0-next's 8, leaves P7/P8's 4 in flight). Never drained to 0.
  for (int i = 0; i < 8; ++i) {
    const int tA1 = 2 * i + 1;
    const int tN0 = (2 * i + 2) & 15;
    const int tN1 = (2 * i + 3) & 15;

    // P1: buf0 (M0,N0)
    LOAD_A(0, 0); LOAD_B(0, 0, bA0, bA1); STAGE_A(1, tA1, 0);
    BAR(); MFMA_Q(0, 0, bA0, bA1); BAR();
    // P2: buf0 (M0,N1)
    LOAD_B(0, 1, bB0, bB1); STAGE_A(1, tA1, 1);
    BAR(); MFMA_Q(0, 1, bB0, bB1); BAR();
    // P3: buf0 (M1,N0)
    LOAD_A(0, 1); STAGE_B(0, tN0, 0);
    BAR(); MFMA_Q(1, 0, bA0, bA1); BAR();
    // P4: buf0 (M1,N1) + gate for buf1
    STAGE_B(0, tN0, 1);
    BAR(); MFMA_Q(1, 1, bB0, bB1); VMW(4); BAR();
    // P5: buf1 (M0,N0)
    LOAD_A(1, 0); LOAD_B(1, 0, bA0, bA1); STAGE_A(0, tN0, 0);
    BAR(); MFMA_Q(0, 0, bA0, bA1); BAR();
    // P6: buf1 (M0,N1)
    LOAD_B(1, 1, bB0, bB1); STAGE_A(0, tN0, 1);
    BAR(); MFMA_Q(0, 1, bB0, bB1); BAR();
    // P7: buf1 (M1,N0)
    LOAD_A(1, 1); STAGE_B(1, tN1, 0);
    BAR(); MFMA_Q(1, 0, bA0, bA1); BAR();
    // P8: buf1 (M1,N1) + gate for next buf0
    STAGE_B(1, tN1, 1);
    BAR(); MFMA_Q(1, 1, bB0, bB1); VMW(4); BAR();
  }

  // ---- epilogue: drain remaining staging DMA, write C.
  VMW(0);
  // C/D layout (m89): col = lane&15, row = (lane>>4)*4 + reg.
  float* Crow = C + (size_t)(bm0 + wm * 128 + lq * 4) * NOUT + bn0 + wn * 64 + l15;
#pragma unroll
  for (int mf = 0; mf < 8; ++mf)
#pragma unroll
    for (int nf = 0; nf < 4; ++nf)
#pragma unroll
      for (int j = 0; j < 4; ++j)
        Crow[(size_t)(mf * 16 + j) * NOUT + nf * 16] = acc[mf][nf][j];

#undef LOAD_A
#undef LOAD_B
#undef STAGE_A
#undef STAGE_B
#undef MFMA_Q
}

extern "C" void kernel_launch(void* const* d_in, const int* in_sizes, int n_in,
                              void* d_out, int out_size, void* d_ws, size_t ws_size,
                              hipStream_t stream) {
  const float* x   = (const float*)d_in[0];   // [4,2048,4096] f32
  const float* sv  = (const float*)d_in[1];   // [4096,1024] f32
  const void*  idx = d_in[2];                 // [1024] int32 or int64
  float* out = (float*)d_out;                 // [4,2048,4096] f32

  unsigned short* xg = (unsigned short*)d_ws;                 // [8192,1024] bf16
  unsigned short* wb = xg + (size_t)MROWS * KDIM;             // [4096,1024] bf16

  gather_x<<<MROWS, 256, 0, stream>>>(x, idx, xg);
  cvt_w<<<(NOUT * KDIM / 4) / 256, 256, 0, stream>>>(sv, wb);

  dim3 grid(NOUT / 256, MROWS / 256);  // (16, 32) = 512 blocks
  gemm256<<<grid, 512, 0, stream>>>(xg, wb, out);
}